// Round 7
// baseline (149.620 us; speedup 1.0000x reference)
//
#include <hip/hip_runtime.h>
#include <hip/hip_bf16.h>
#include <math.h>

#define FH 32
#define FW 88
#define DD 118
#define C_IN 256
#define HID 64
#define C_OUT 80
#define NPIX 5632
#define PIX_PER_B 2816
#define N_R 128
#define N_THETA 256
#define NCOL 176          // B * FW
#define NBIN 32768        // N_R * N_THETA
#define ECAP 12           // entries per bin cap (overflow -> flag -> fallback)
#define PSTRIDE 9440      // DD * C_OUT

typedef __attribute__((ext_vector_type(8))) short short8;
typedef __attribute__((ext_vector_type(4))) float f32x4;

// ---------- dtype adaptivity ----------
__device__ inline float bf2f(unsigned short h) {
  return __uint_as_float((unsigned)h << 16);
}
__device__ inline unsigned short f2bf(float f) {
  unsigned u = __float_as_uint(f);
  unsigned r = (u + 0x7fffu + ((u >> 16) & 1u)) >> 16;   // RNE
  return (unsigned short)r;
}
__device__ inline bool detect_bf16(const void* intr) {
  float f = __uint_as_float(*(const unsigned*)intr);
  return !(f > 300.0f && f < 500.0f);
}
__device__ inline float ldf(const void* p, int i, bool isb) {
  return isb ? bf2f(((const unsigned short*)p)[i]) : ((const float*)p)[i];
}

// ---------- per-block geometry staging (edges + cams) into LDS ----------
__device__ inline void load_geom(int tid, float* radEL, float* angEL, float* camsL,
                                 const void* rots, const void* trans, const void* intr,
                                 bool isb) {
  if (tid < 129) {
    double t = (double)tid * (1.0 / 128.0);
    radEL[tid] = (float)(1.0 + pow(t, 1.5) * 59.0);
  }
  for (int i = tid; i < 257; i += 256) {
    double step = M_PI / 256.0;
    double vv = (i == 256) ? (M_PI / 2.0) : ((double)i * step + (-M_PI / 2.0));
    angEL[i] = (float)vv;
  }
  if (tid < 18) camsL[tid] = ldf(rots, tid, isb);
  if (tid < 6)  camsL[20 + tid] = ldf(trans, tid, isb);
  if (tid >= 6 && tid < 24) camsL[28 + (tid - 6)] = ldf(intr, tid - 6, isb);
}

// ---------- shared geometry: EXACT round-2 numerics (proven absmax 6.1e-5) ----------
__device__ inline int computeBin(int w, int h, int d,
                                 const float* camsF, int b,
                                 const float* radE, const float* angE) {
  float fx = camsF[28 + b * 9 + 0], cx = camsF[28 + b * 9 + 2];
  float fy = camsF[28 + b * 9 + 4], cy = camsF[28 + b * 9 + 5];
  float R00 = camsF[b * 9 + 0], R01 = camsF[b * 9 + 1], R02 = camsF[b * 9 + 2];
  float R10 = camsF[b * 9 + 3], R11 = camsF[b * 9 + 4], R12 = camsF[b * 9 + 5];
  float Tx = camsF[20 + b * 3 + 0], Ty = camsF[20 + b * 3 + 1];
  float u  = (w == FW - 1) ? 703.0f : (float)((double)w * (703.0 / 87.0));
  float vv = (h == FH - 1) ? 255.0f : (float)((double)h * (255.0 / 31.0));
  float dd = 1.0f + 0.5f * (float)d;
  float px = __fdiv_rn(__fmul_rn(__fsub_rn(u, cx), dd), fx);
  float py = __fdiv_rn(__fmul_rn(__fsub_rn(vv, cy), dd), fy);
  float xl = __fadd_rn(__fadd_rn(__fadd_rn(__fmul_rn(R00, px), __fmul_rn(R01, py)),
                                 __fmul_rn(R02, dd)), Tx);
  float yl = __fadd_rn(__fadd_rn(__fadd_rn(__fmul_rn(R10, px), __fmul_rn(R11, py)),
                                 __fmul_rn(R12, dd)), Ty);
  float r = __fsqrt_rn(__fadd_rn(__fmul_rn(xl, xl), __fmul_rn(yl, yl)));
  float th = (float)atan2((double)yl, (double)xl);
  int lo = 0, hi = 129;
  while (lo < hi) { int mid = (lo + hi) >> 1; if (radE[mid] <= r) lo = mid + 1; else hi = mid; }
  int ri = lo - 1;
  lo = 0; hi = 257;
  while (lo < hi) { int mid = (lo + hi) >> 1; if (angE[mid] <= th) lo = mid + 1; else hi = mid; }
  int ti = lo - 1;
  bool valid = (ri >= 0) && (ri < N_R) && (ti >= 0) && (ti < N_THETA);
  return valid ? (ri * N_THETA + ti) : -1;
}

// ==================== verbatim phase bodies (fallback + outg) ====================

__device__ __forceinline__ void dev_bins(
    int blk_rel, int tid, float* radEL, float* angEL, float* camsL,
    const void* rots, const void* trans, const void* intr, bool isb,
    int* __restrict__ cnt, unsigned* __restrict__ ent, int* __restrict__ flag) {
  int t = blk_rel * 256 + tid;
  load_geom(tid, radEL, angEL, camsL, rots, trans, intr, isb);
  __syncthreads();
  if (t < NCOL * DD) {
    int col = t / DD, d = t - col * DD;
    int b = col / FW, w = col - b * FW;
    float R01 = camsL[b * 9 + 1], R11 = camsL[b * 9 + 4];
    if (!(R01 == 0.0f && R11 == 0.0f)) atomicOr(flag, 1);
    int bin = computeBin(w, 0, d, camsL, b, radEL, angEL);
    if (bin >= 0) {
      int slot = atomicAdd(&cnt[b * NBIN + bin], 1);
      if (slot < ECAP) ent[(size_t)(b * NBIN + bin) * ECAP + slot] = ((unsigned)col << 8) | (unsigned)d;
      else atomicOr(flag, 1);
    }
  }
}

__device__ __forceinline__ void dev_scatter(
    int idx2, int tid, float* depthL, float* featL,
    float* radEL, float* angEL, float* camsL,
    const void* rots, const void* trans, const void* intr, bool isb,
    const float* __restrict__ depthW, const float* __restrict__ featW,
    float* __restrict__ bevAcc) {
  int col = idx2 >> 1, chalf = idx2 & 1;
  int b = col / FW, w = col - b * FW;
  load_geom(tid, radEL, angEL, camsL, rots, trans, intr, isb);
  size_t colPix = (size_t)b * PIX_PER_B + w;
  for (int i = tid; i < FH * DD; i += 256) {
    int h = i / DD, d = i - h * DD;
    depthL[d * 33 + h] = depthW[(colPix + (size_t)h * FW) * DD + d];
  }
  for (int i = tid; i < FH * C_OUT; i += 256) {
    int h = i / C_OUT, c = i - h * C_OUT;
    featL[i] = featW[(colPix + (size_t)h * FW) * C_OUT + c];
  }
  __syncthreads();
  const float4* featL4 = (const float4*)featL;
  for (int t = tid; t < DD * FH * 10; t += 256) {
    int d = t / 320, rem = t - d * 320;
    int h = rem / 10, c4 = chalf * 10 + (rem - (rem / 10) * 10);
    int bin = computeBin(w, h, d, camsL, b, radEL, angEL);
    if (bin < 0) continue;
    float wd = depthL[d * 33 + h];
    float4 f = featL4[h * 20 + c4];
    float* outb = bevAcc + (((size_t)(b * C_OUT + c4 * 4)) << 15) + bin;
    unsafeAtomicAdd(outb, wd * f.x);
    unsafeAtomicAdd(outb + (1u << 15), wd * f.y);
    unsafeAtomicAdd(outb + (2u << 15), wd * f.z);
    unsafeAtomicAdd(outb + (3u << 15), wd * f.w);
  }
}

// outg split-c4 (proven round-6): per-(bin,c4) summation order unchanged.
__device__ __forceinline__ void dev_out_rng(
    int vt, int tid, int c4lo, int c4hi, const float* __restrict__ P,
    const int* __restrict__ cnt, const unsigned* __restrict__ ent,
    void* __restrict__ out, bool isb) {
  int b = vt >> 7;                 // vt in [0, 256): 128 tasks per batch
  int ri = vt & 127;
  int bin = ri * N_THETA + tid;
  int n = cnt[b * NBIN + bin];
  if (n > ECAP) n = ECAP;
  unsigned ee[ECAP];
  const unsigned* eb = ent + (size_t)(b * NBIN + bin) * ECAP;
  for (int i = 0; i < n; i++) ee[i] = eb[i];
  for (int i = 1; i < n; i++) {            // sort asc (col,d) -> deterministic sum order
    unsigned key = ee[i]; int j = i - 1;
    while (j >= 0 && ee[j] > key) { ee[j + 1] = ee[j]; j--; }
    ee[j + 1] = key;
  }
  int base[ECAP];
  for (int i = 0; i < n; i++)
    base[i] = (int)(((ee[i] >> 8) * PSTRIDE + (ee[i] & 255u) * C_OUT) >> 2);  // float4 idx
  const float4* P4 = (const float4*)P;
  unsigned short* oh = (unsigned short*)out;
  float* of = (float*)out;
  size_t obase = (((size_t)(b * C_OUT)) << 15) + bin;
  for (int c4 = c4lo; c4 < c4hi; c4++) {
    float4 s = make_float4(0.f, 0.f, 0.f, 0.f);
    for (int i = 0; i < n; i++) {
      float4 v = P4[base[i] + c4];
      s.x += v.x; s.y += v.y; s.z += v.z; s.w += v.w;
    }
    size_t o0 = obase + ((size_t)(c4 * 4) << 15);
    if (isb) {
      oh[o0]              = f2bf(s.x);
      oh[o0 + (1u << 15)] = f2bf(s.y);
      oh[o0 + (2u << 15)] = f2bf(s.z);
      oh[o0 + (3u << 15)] = f2bf(s.w);
    } else {
      of[o0]              = s.x;
      of[o0 + (1u << 15)] = s.y;
      of[o0 + (2u << 15)] = s.z;
      of[o0 + (3u << 15)] = s.w;
    }
  }
}

__device__ __forceinline__ void dev_out_copy(
    int gtid, int gstride, const float* __restrict__ bevAcc,
    void* __restrict__ out, bool isb) {
  const float4* a4 = (const float4*)bevAcc;
  int n4 = (NBIN * 2 * C_OUT) / 4;
  if (isb) {
    ushort4* o4 = (ushort4*)out;
    for (int i = gtid; i < n4; i += gstride) {
      float4 v = a4[i];
      ushort4 o; o.x = f2bf(v.x); o.y = f2bf(v.y); o.z = f2bf(v.z); o.w = f2bf(v.w);
      o4[i] = o;
    }
  } else {
    float4* o4 = (float4*)out;
    for (int i = gtid; i < n4; i += gstride) o4[i] = a4[i];
  }
}

// ==================== K1: fused column MLP+PCOL (176) || bins (82) ====================
// Column block: 2 MFMA tiles (16 h-pixels each; pixel = independent MFMA column
// -> per-pixel math identical to proven k_mlp). Softmax epilogue writes depth/
// feat to BOTH global (fallback insurance) and LDS; pcol compute tail verbatim
// from proven dev_pcol, reading LDS -> eliminates the 4.5 MB cold re-read.
__global__ __launch_bounds__(256) void k_f1(
    const void* __restrict__ xraw,
    const void* __restrict__ rots, const void* __restrict__ trans,
    const void* __restrict__ intr,
    const void* __restrict__ w1r, const void* __restrict__ b1r,
    const void* __restrict__ g1r, const void* __restrict__ be1r,
    const void* __restrict__ m1r, const void* __restrict__ v1r,
    const void* __restrict__ w2r, const void* __restrict__ b2r,
    const void* __restrict__ g2r, const void* __restrict__ be2r,
    const void* __restrict__ m2r, const void* __restrict__ v2r,
    int* __restrict__ cnt, unsigned* __restrict__ ent, int* __restrict__ flag,
    float* __restrict__ depthW, float* __restrict__ featW,
    float* __restrict__ P) {
  __shared__ __align__(16) float shbuf[3712];
  __shared__ __align__(16) float h1L[16 * 68];
  __shared__ float inv1L[64], b1fL[64], inv2L[198], b2fL[198];
  __shared__ __align__(16) float depthL[32 * 120];
  __shared__ __align__(16) float featL[32 * 80];
  __shared__ float radEL[129], angEL[257], camsL[46];
  int tid = threadIdx.x;
  bool isb = detect_bf16(intr);

  if (blockIdx.x >= 176) {
    dev_bins(blockIdx.x - 176, tid, radEL, angEL, camsL,
             rots, trans, intr, isb, cnt, ent, flag);
    return;
  }

  // XCD-chunked swizzle: hw round-robins bid->XCD; give each XCD a contiguous
  // 22-column chunk so the 32 columns sharing an x cache line span few L2s.
  int col = (blockIdx.x & 7) * 22 + (blockIdx.x >> 3);   // bijective, 176 = 8*22
  int b = col / FW, w = col - b * FW;

  // ---- param staging (once per block; verbatim) ----
  if (tid < 64) {
    float iv = ldf(g1r, tid, isb) / sqrtf(ldf(v1r, tid, isb) + 1e-5f);
    inv1L[tid] = iv;
    b1fL[tid] = ldf(b1r, tid, isb) * iv + (ldf(be1r, tid, isb) - ldf(m1r, tid, isb) * iv);
  }
  if (tid < 198) {
    float iv = ldf(g2r, tid, isb) / sqrtf(ldf(v2r, tid, isb) + 1e-5f);
    inv2L[tid] = iv;
    b2fL[tid] = ldf(b2r, tid, isb) * iv + (ldf(be2r, tid, isb) - ldf(m2r, tid, isb) * iv);
  }

  // ---- w1 fragments (once; identical for both tiles; verbatim) ----
  int lane = tid & 63, wv = tid >> 6;
  int nloc = lane & 15, quad = lane >> 4;
  int orow = wv * 16 + nloc;
  short8 afr[8];
  const unsigned short* w1h = (const unsigned short*)w1r;
  const float* w1f32 = (const float*)w1r;
  if (isb) {
#pragma unroll
    for (int s = 0; s < 8; s++)
      afr[s] = *(const short8*)(w1h + orow * 256 + s * 32 + quad * 8);
  } else {
#pragma unroll
    for (int s = 0; s < 8; s++) {
      short8 a;
#pragma unroll
      for (int j = 0; j < 8; j++)
        a[j] = (short)f2bf(w1f32[orow * 256 + s * 32 + quad * 8 + j]);
      afr[s] = a;
    }
  }

  unsigned short* xsU = (unsigned short*)shbuf;
  float* h2s = shbuf;
  float* smaxL = shbuf + 3200;
  float* ssumL = shbuf + 3456;
  const unsigned short* xh = (const unsigned short*)xraw;
  const float* xf = (const float*)xraw;

  for (int t = 0; t < 2; ++t) {
    // ---- x staging: pixel p <-> h = t*16+p of this column ----
    {
      int p = tid & 15, crow = tid >> 4;
      size_t xb = (size_t)b * C_IN * PIX_PER_B + (size_t)(t * 16) * FW + w;
      for (int it = 0; it < 16; it++) {
        int c = it * 16 + crow;
        size_t gi = xb + (size_t)c * PIX_PER_B + (size_t)(tid & 15) * FW;
        xsU[p * 264 + c] = isb ? xh[gi] : f2bf(xf[gi]);
      }
    }
    __syncthreads();
    // ---- mlp1 MFMA (verbatim) ----
    f32x4 acc = {0.f, 0.f, 0.f, 0.f};
#pragma unroll
    for (int s = 0; s < 8; s++) {
      short8 bfr = *(const short8*)(xsU + nloc * 264 + s * 32 + quad * 8);
      acc = __builtin_amdgcn_mfma_f32_16x16x32_bf16(afr[s], bfr, acc, 0, 0, 0);
    }
#pragma unroll
    for (int r = 0; r < 4; r++) {
      int mm = wv * 16 + quad * 4 + r;
      float hv = fmaxf(fmaf(acc[r], inv1L[mm], b1fL[mm]), 0.f);
      h1L[nloc * 68 + mm] = hv;
    }
    __syncthreads();
    // ---- mlp2 (verbatim) ----
    int p = tid & 15, g = tid >> 4;
    float h1v[64];
    const float4* hp = (const float4*)(h1L + p * 68);
#pragma unroll
    for (int k4 = 0; k4 < 16; k4++) {
      float4 hv = hp[k4];
      h1v[4 * k4 + 0] = hv.x; h1v[4 * k4 + 1] = hv.y;
      h1v[4 * k4 + 2] = hv.z; h1v[4 * k4 + 3] = hv.w;
    }
    for (int j = 0; j < 13; j++) {
      int o = g * 13 + j;
      if (o < 198) {
        float iv = inv2L[o];
        float q0 = 0.f, q1 = 0.f, q2 = 0.f, q3 = 0.f;
        if (isb) {
          const ushort4* wr = (const ushort4*)w2r;
#pragma unroll
          for (int k4 = 0; k4 < 16; k4 += 4) {
            ushort4 u0 = wr[o * 16 + k4 + 0];
            ushort4 u1 = wr[o * 16 + k4 + 1];
            ushort4 u2 = wr[o * 16 + k4 + 2];
            ushort4 u3 = wr[o * 16 + k4 + 3];
            q0 = fmaf(bf2f(u0.x) * iv, h1v[4 * k4 + 0], q0);
            q0 = fmaf(bf2f(u0.y) * iv, h1v[4 * k4 + 1], q0);
            q0 = fmaf(bf2f(u0.z) * iv, h1v[4 * k4 + 2], q0);
            q0 = fmaf(bf2f(u0.w) * iv, h1v[4 * k4 + 3], q0);
            q1 = fmaf(bf2f(u1.x) * iv, h1v[4 * k4 + 4], q1);
            q1 = fmaf(bf2f(u1.y) * iv, h1v[4 * k4 + 5], q1);
            q1 = fmaf(bf2f(u1.z) * iv, h1v[4 * k4 + 6], q1);
            q1 = fmaf(bf2f(u1.w) * iv, h1v[4 * k4 + 7], q1);
            q2 = fmaf(bf2f(u2.x) * iv, h1v[4 * k4 + 8], q2);
            q2 = fmaf(bf2f(u2.y) * iv, h1v[4 * k4 + 9], q2);
            q2 = fmaf(bf2f(u2.z) * iv, h1v[4 * k4 + 10], q2);
            q2 = fmaf(bf2f(u2.w) * iv, h1v[4 * k4 + 11], q2);
            q3 = fmaf(bf2f(u3.x) * iv, h1v[4 * k4 + 12], q3);
            q3 = fmaf(bf2f(u3.y) * iv, h1v[4 * k4 + 13], q3);
            q3 = fmaf(bf2f(u3.z) * iv, h1v[4 * k4 + 14], q3);
            q3 = fmaf(bf2f(u3.w) * iv, h1v[4 * k4 + 15], q3);
          }
        } else {
          const float4* wr = (const float4*)w2r;
#pragma unroll
          for (int k4 = 0; k4 < 16; k4 += 4) {
            float4 w0 = wr[o * 16 + k4 + 0];
            float4 w1v = wr[o * 16 + k4 + 1];
            float4 w2v = wr[o * 16 + k4 + 2];
            float4 w3v = wr[o * 16 + k4 + 3];
            q0 = fmaf(w0.x * iv, h1v[4 * k4 + 0], q0);
            q0 = fmaf(w0.y * iv, h1v[4 * k4 + 1], q0);
            q0 = fmaf(w0.z * iv, h1v[4 * k4 + 2], q0);
            q0 = fmaf(w0.w * iv, h1v[4 * k4 + 3], q0);
            q1 = fmaf(w1v.x * iv, h1v[4 * k4 + 4], q1);
            q1 = fmaf(w1v.y * iv, h1v[4 * k4 + 5], q1);
            q1 = fmaf(w1v.z * iv, h1v[4 * k4 + 6], q1);
            q1 = fmaf(w1v.w * iv, h1v[4 * k4 + 7], q1);
            q2 = fmaf(w2v.x * iv, h1v[4 * k4 + 8], q2);
            q2 = fmaf(w2v.y * iv, h1v[4 * k4 + 9], q2);
            q2 = fmaf(w2v.z * iv, h1v[4 * k4 + 10], q2);
            q2 = fmaf(w2v.w * iv, h1v[4 * k4 + 11], q2);
            q3 = fmaf(w3v.x * iv, h1v[4 * k4 + 12], q3);
            q3 = fmaf(w3v.y * iv, h1v[4 * k4 + 13], q3);
            q3 = fmaf(w3v.z * iv, h1v[4 * k4 + 14], q3);
            q3 = fmaf(w3v.w * iv, h1v[4 * k4 + 15], q3);
          }
        }
        h2s[o * 16 + p] = b2fL[o] + ((q0 + q1) + (q2 + q3));
      }
    }
    __syncthreads();
    // ---- softmax (verbatim) ----
    int r0 = g * 8, r1 = min(118, r0 + 8);
    float lm = -INFINITY;
    for (int o = r0; o < r1; o++) lm = fmaxf(lm, h2s[o * 16 + p]);
    smaxL[g * 16 + p] = lm;
    __syncthreads();
    float m = smaxL[p];
#pragma unroll
    for (int gg = 1; gg < 16; gg++) m = fmaxf(m, smaxL[gg * 16 + p]);
    float ls = 0.f;
    for (int o = r0; o < r1; o++) ls += expf(h2s[o * 16 + p] - m);
    ssumL[g * 16 + p] = ls;
    __syncthreads();
    float tot = 0.f;
#pragma unroll
    for (int gg = 0; gg < 16; gg++) tot += ssumL[gg * 16 + p];
    // ---- epilogue: dual write (global for fallback, LDS for pcol) ----
    int h = t * 16 + p;
    size_t pix = (size_t)b * PIX_PER_B + (size_t)h * FW + w;
    for (int o = r0; o < r1; o++) {
      float dv = expf(h2s[o * 16 + p] - m) / tot;
      depthW[pix * DD + o] = dv;
      depthL[h * 120 + o] = dv;
    }
    int f0 = g * 5;
    for (int f = f0; f < f0 + 5; f++) {
      float fv = h2s[(118 + f) * 16 + p];
      featW[pix * C_OUT + f] = fv;
      featL[h * 80 + f] = fv;
    }
    __syncthreads();   // shbuf reused by next tile / pcol reads depthL+featL
  }

  // ---- pcol compute tail (verbatim from proven dev_pcol) ----
  const float4* featL4 = (const float4*)featL;
  const float4* depthL4 = (const float4*)depthL;   // [h][30] quads
  float4* P4 = (float4*)(P + (size_t)col * PSTRIDE);
  for (int t2 = tid; t2 < 30 * 20; t2 += 256) {
    int dq = t2 / 20, c4 = t2 - dq * 20;
    float4 a0 = make_float4(0.f, 0.f, 0.f, 0.f);
    float4 a1 = make_float4(0.f, 0.f, 0.f, 0.f);
    float4 a2 = make_float4(0.f, 0.f, 0.f, 0.f);
    float4 a3 = make_float4(0.f, 0.f, 0.f, 0.f);
#pragma unroll
    for (int h = 0; h < FH; h++) {
      float4 wd = depthL4[h * 30 + dq];
      float4 f = featL4[h * 20 + c4];
      a0.x = fmaf(wd.x, f.x, a0.x); a0.y = fmaf(wd.x, f.y, a0.y);
      a0.z = fmaf(wd.x, f.z, a0.z); a0.w = fmaf(wd.x, f.w, a0.w);
      a1.x = fmaf(wd.y, f.x, a1.x); a1.y = fmaf(wd.y, f.y, a1.y);
      a1.z = fmaf(wd.y, f.z, a1.z); a1.w = fmaf(wd.y, f.w, a1.w);
      a2.x = fmaf(wd.z, f.x, a2.x); a2.y = fmaf(wd.z, f.y, a2.y);
      a2.z = fmaf(wd.z, f.z, a2.z); a2.w = fmaf(wd.z, f.w, a2.w);
      a3.x = fmaf(wd.w, f.x, a3.x); a3.y = fmaf(wd.w, f.y, a3.y);
      a3.z = fmaf(wd.w, f.z, a3.z); a3.w = fmaf(wd.w, f.w, a3.w);
    }
    int d0 = dq * 4;
    P4[(d0 + 0) * 20 + c4] = a0;
    P4[(d0 + 1) * 20 + c4] = a1;
    if (d0 + 2 < DD) {
      P4[(d0 + 2) * 20 + c4] = a2;
      P4[(d0 + 3) * 20 + c4] = a3;
    }
  }
}

// ==================== K2: outg (512) || flag-guarded bevAcc zero (64) ====================
__global__ __launch_bounds__(256) void k_f2(
    const float* __restrict__ P, const int* __restrict__ cnt,
    const unsigned* __restrict__ ent, const int* __restrict__ flag,
    float* __restrict__ bevAcc, void* __restrict__ out,
    const void* __restrict__ intrRaw) {
  int tid = threadIdx.x;
  if (blockIdx.x >= 512) {
    if (*flag == 0) return;               // happy path: no 21 MB zero
    float4 z = make_float4(0.f, 0.f, 0.f, 0.f);
    float4* bz = (float4*)bevAcc;
    int n4 = (NBIN * 2 * C_OUT) / 4;
    for (int i = (blockIdx.x - 512) * 256 + tid; i < n4; i += 64 * 256) bz[i] = z;
    return;
  }
  if (*flag != 0) return;
  bool isb = detect_bf16(intrRaw);
  int half = blockIdx.x & 1;
  dev_out_rng(blockIdx.x >> 1, tid, half * 10, half * 10 + 10,
              P, cnt, ent, out, isb);
}

// ==================== K3: flag-guarded scatter (352) ====================
__global__ __launch_bounds__(256) void k_f3(
    const float* __restrict__ depthW, const float* __restrict__ featW,
    const int* __restrict__ flag,
    const void* __restrict__ rots, const void* __restrict__ trans,
    const void* __restrict__ intr, float* __restrict__ bevAcc) {
  __shared__ __align__(16) float depthL[DD * 33];
  __shared__ __align__(16) float featL[FH * C_OUT];
  __shared__ float radEL[129], angEL[257], camsL[46];
  if (*flag == 0) return;
  bool isb = detect_bf16(intr);
  dev_scatter(blockIdx.x, threadIdx.x, depthL, featL, radEL, angEL, camsL,
              rots, trans, intr, isb, depthW, featW, bevAcc);
}

// ==================== K4: flag-guarded copy (1024) ====================
__global__ __launch_bounds__(256) void k_f4(
    const float* __restrict__ bevAcc, const int* __restrict__ flag,
    void* __restrict__ out, const void* __restrict__ intrRaw) {
  if (*flag == 0) return;
  bool isb = detect_bf16(intrRaw);
  dev_out_copy(blockIdx.x * 256 + threadIdx.x, 1024 * 256, bevAcc, out, isb);
}

extern "C" void kernel_launch(void* const* d_in, const int* in_sizes, int n_in,
                              void* d_out, int out_size, void* d_ws, size_t ws_size,
                              hipStream_t stream) {
  const void* x     = d_in[0];
  const void* rots  = d_in[1];
  const void* trans = d_in[2];
  const void* intr  = d_in[3];
  const void* w1  = d_in[4];
  const void* b1  = d_in[5];
  const void* g1  = d_in[6];
  const void* be1 = d_in[7];
  const void* m1  = d_in[8];
  const void* v1  = d_in[9];
  const void* w2  = d_in[10];
  const void* b2  = d_in[11];
  const void* g2  = d_in[12];
  const void* be2 = d_in[13];
  const void* m2  = d_in[14];
  const void* v2  = d_in[15];

  float* ws = (float*)d_ws;                     // offsets in floats
  float*    P      = ws + 0;                    // 1,661,440 f
  int*      cnt    = (int*)(ws + 1661440);      // 65,536 i
  int*      flag   = (int*)(ws + 1726976);      // 1 i (reserve 64; contiguous after cnt)
  unsigned* ent    = (unsigned*)(ws + 1727040); // 786,432 u32 -> ends 2,513,472
  float*    depthW = ws + 2513472;              // 664,576 f
  float*    featW  = ws + 3178048;              // 450,560 f
  float*    bevAcc = ws + 3628608;              // 5,242,880 f -> total 8,871,488 f (~35.5 MB)

  (void)hipMemsetAsync(cnt, 0, (size_t)(65536 + 64) * sizeof(int), stream);

  k_f1<<<258, 256, 0, stream>>>(x, rots, trans, intr,
                                w1, b1, g1, be1, m1, v1,
                                w2, b2, g2, be2, m2, v2,
                                cnt, ent, flag, depthW, featW, P);
  k_f2<<<576, 256, 0, stream>>>(P, cnt, ent, flag, bevAcc, d_out, intr);
  k_f3<<<352, 256, 0, stream>>>(depthW, featW, flag, rots, trans, intr, bevAcc);
  k_f4<<<1024, 256, 0, stream>>>(bevAcc, flag, d_out, intr);
}

// Round 8
// 149.360 us; speedup vs baseline: 1.0017x; 1.0017x over previous
//
#include <hip/hip_runtime.h>
#include <hip/hip_bf16.h>
#include <math.h>

#define FH 32
#define FW 88
#define DD 118
#define C_IN 256
#define HID 64
#define C_OUT 80
#define NPIX 5632
#define PIX_PER_B 2816
#define N_R 128
#define N_THETA 256
#define NCOL 176          // B * FW
#define NBIN 32768        // N_R * N_THETA
#define ECAP 12           // entries per bin cap (overflow -> flag -> fallback)
#define PSTRIDE 9440      // DD * C_OUT

typedef __attribute__((ext_vector_type(8))) short short8;
typedef __attribute__((ext_vector_type(4))) float f32x4;

// ---------- dtype adaptivity ----------
__device__ inline float bf2f(unsigned short h) {
  return __uint_as_float((unsigned)h << 16);
}
__device__ inline unsigned short f2bf(float f) {
  unsigned u = __float_as_uint(f);
  unsigned r = (u + 0x7fffu + ((u >> 16) & 1u)) >> 16;   // RNE
  return (unsigned short)r;
}
__device__ inline bool detect_bf16(const void* intr) {
  float f = __uint_as_float(*(const unsigned*)intr);
  return !(f > 300.0f && f < 500.0f);
}
__device__ inline float ldf(const void* p, int i, bool isb) {
  return isb ? bf2f(((const unsigned short*)p)[i]) : ((const float*)p)[i];
}

// ---------- per-block geometry staging (edges + cams) into LDS ----------
__device__ inline void load_geom(int tid, float* radEL, float* angEL, float* camsL,
                                 const void* rots, const void* trans, const void* intr,
                                 bool isb) {
  if (tid < 129) {
    double t = (double)tid * (1.0 / 128.0);
    radEL[tid] = (float)(1.0 + pow(t, 1.5) * 59.0);
  }
  for (int i = tid; i < 257; i += 256) {
    double step = M_PI / 256.0;
    double vv = (i == 256) ? (M_PI / 2.0) : ((double)i * step + (-M_PI / 2.0));
    angEL[i] = (float)vv;
  }
  if (tid < 18) camsL[tid] = ldf(rots, tid, isb);
  if (tid < 6)  camsL[20 + tid] = ldf(trans, tid, isb);
  if (tid >= 6 && tid < 24) camsL[28 + (tid - 6)] = ldf(intr, tid - 6, isb);
}

// ---------- shared geometry: EXACT round-2 numerics (proven absmax 6.1e-5) ----------
__device__ inline int computeBin(int w, int h, int d,
                                 const float* camsF, int b,
                                 const float* radE, const float* angE) {
  float fx = camsF[28 + b * 9 + 0], cx = camsF[28 + b * 9 + 2];
  float fy = camsF[28 + b * 9 + 4], cy = camsF[28 + b * 9 + 5];
  float R00 = camsF[b * 9 + 0], R01 = camsF[b * 9 + 1], R02 = camsF[b * 9 + 2];
  float R10 = camsF[b * 9 + 3], R11 = camsF[b * 9 + 4], R12 = camsF[b * 9 + 5];
  float Tx = camsF[20 + b * 3 + 0], Ty = camsF[20 + b * 3 + 1];
  float u  = (w == FW - 1) ? 703.0f : (float)((double)w * (703.0 / 87.0));
  float vv = (h == FH - 1) ? 255.0f : (float)((double)h * (255.0 / 31.0));
  float dd = 1.0f + 0.5f * (float)d;
  float px = __fdiv_rn(__fmul_rn(__fsub_rn(u, cx), dd), fx);
  float py = __fdiv_rn(__fmul_rn(__fsub_rn(vv, cy), dd), fy);
  float xl = __fadd_rn(__fadd_rn(__fadd_rn(__fmul_rn(R00, px), __fmul_rn(R01, py)),
                                 __fmul_rn(R02, dd)), Tx);
  float yl = __fadd_rn(__fadd_rn(__fadd_rn(__fmul_rn(R10, px), __fmul_rn(R11, py)),
                                 __fmul_rn(R12, dd)), Ty);
  float r = __fsqrt_rn(__fadd_rn(__fmul_rn(xl, xl), __fmul_rn(yl, yl)));
  float th = (float)atan2((double)yl, (double)xl);
  int lo = 0, hi = 129;
  while (lo < hi) { int mid = (lo + hi) >> 1; if (radE[mid] <= r) lo = mid + 1; else hi = mid; }
  int ri = lo - 1;
  lo = 0; hi = 257;
  while (lo < hi) { int mid = (lo + hi) >> 1; if (angE[mid] <= th) lo = mid + 1; else hi = mid; }
  int ti = lo - 1;
  bool valid = (ri >= 0) && (ri < N_R) && (ti >= 0) && (ti < N_THETA);
  return valid ? (ri * N_THETA + ti) : -1;
}

// ==================== bins (verbatim) ====================
__device__ __forceinline__ void dev_bins(
    int blk_rel, int tid, float* radEL, float* angEL, float* camsL,
    const void* rots, const void* trans, const void* intr, bool isb,
    int* __restrict__ cnt, unsigned* __restrict__ ent, int* __restrict__ flag) {
  int t = blk_rel * 256 + tid;
  load_geom(tid, radEL, angEL, camsL, rots, trans, intr, isb);
  __syncthreads();
  if (t < NCOL * DD) {
    int col = t / DD, d = t - col * DD;
    int b = col / FW, w = col - b * FW;
    float R01 = camsL[b * 9 + 1], R11 = camsL[b * 9 + 4];
    if (!(R01 == 0.0f && R11 == 0.0f)) atomicOr(flag, 1);
    int bin = computeBin(w, 0, d, camsL, b, radEL, angEL);
    if (bin >= 0) {
      int slot = atomicAdd(&cnt[b * NBIN + bin], 1);
      if (slot < ECAP) ent[(size_t)(b * NBIN + bin) * ECAP + slot] = ((unsigned)col << 8) | (unsigned)d;
      else atomicOr(flag, 1);
    }
  }
}

// ==================== column MLP -> LDS (verbatim round-7 math; layout-templated) ====================
// DLAY 0: depthL[h*120+o] (pcol layout).  DLAY 1: depthL[o*33+h] (scatter layout).
// featL[h*80+f] in both. Global depth/feat writes REMOVED (fallback recomputes).
template<int DLAY>
__device__ __forceinline__ void dev_mlp_col(
    int b, int w, int tid, float* shbuf, float* h1L,
    float* inv1L, float* b1fL, float* inv2L, float* b2fL,
    float* depthL, float* featL,
    const void* __restrict__ xraw,
    const void* __restrict__ w1r, const void* __restrict__ b1r,
    const void* __restrict__ g1r, const void* __restrict__ be1r,
    const void* __restrict__ m1r, const void* __restrict__ v1r,
    const void* __restrict__ w2r, const void* __restrict__ b2r,
    const void* __restrict__ g2r, const void* __restrict__ be2r,
    const void* __restrict__ m2r, const void* __restrict__ v2r, bool isb) {
  if (tid < 64) {
    float iv = ldf(g1r, tid, isb) / sqrtf(ldf(v1r, tid, isb) + 1e-5f);
    inv1L[tid] = iv;
    b1fL[tid] = ldf(b1r, tid, isb) * iv + (ldf(be1r, tid, isb) - ldf(m1r, tid, isb) * iv);
  }
  if (tid < 198) {
    float iv = ldf(g2r, tid, isb) / sqrtf(ldf(v2r, tid, isb) + 1e-5f);
    inv2L[tid] = iv;
    b2fL[tid] = ldf(b2r, tid, isb) * iv + (ldf(be2r, tid, isb) - ldf(m2r, tid, isb) * iv);
  }
  int lane = tid & 63, wv = tid >> 6;
  int nloc = lane & 15, quad = lane >> 4;
  int orow = wv * 16 + nloc;
  short8 afr[8];
  const unsigned short* w1h = (const unsigned short*)w1r;
  const float* w1f32 = (const float*)w1r;
  if (isb) {
#pragma unroll
    for (int s = 0; s < 8; s++)
      afr[s] = *(const short8*)(w1h + orow * 256 + s * 32 + quad * 8);
  } else {
#pragma unroll
    for (int s = 0; s < 8; s++) {
      short8 a;
#pragma unroll
      for (int j = 0; j < 8; j++)
        a[j] = (short)f2bf(w1f32[orow * 256 + s * 32 + quad * 8 + j]);
      afr[s] = a;
    }
  }
  unsigned short* xsU = (unsigned short*)shbuf;
  float* h2s = shbuf;
  float* smaxL = shbuf + 3200;
  float* ssumL = shbuf + 3456;
  const unsigned short* xh = (const unsigned short*)xraw;
  const float* xf = (const float*)xraw;

  for (int t = 0; t < 2; ++t) {
    {
      int p = tid & 15, crow = tid >> 4;
      size_t xb = (size_t)b * C_IN * PIX_PER_B + (size_t)(t * 16) * FW + w;
      for (int it = 0; it < 16; it++) {
        int c = it * 16 + crow;
        size_t gi = xb + (size_t)c * PIX_PER_B + (size_t)(tid & 15) * FW;
        xsU[p * 264 + c] = isb ? xh[gi] : f2bf(xf[gi]);
      }
    }
    __syncthreads();
    f32x4 acc = {0.f, 0.f, 0.f, 0.f};
#pragma unroll
    for (int s = 0; s < 8; s++) {
      short8 bfr = *(const short8*)(xsU + nloc * 264 + s * 32 + quad * 8);
      acc = __builtin_amdgcn_mfma_f32_16x16x32_bf16(afr[s], bfr, acc, 0, 0, 0);
    }
#pragma unroll
    for (int r = 0; r < 4; r++) {
      int mm = wv * 16 + quad * 4 + r;
      float hv = fmaxf(fmaf(acc[r], inv1L[mm], b1fL[mm]), 0.f);
      h1L[nloc * 68 + mm] = hv;
    }
    __syncthreads();
    int p = tid & 15, g = tid >> 4;
    float h1v[64];
    const float4* hp = (const float4*)(h1L + p * 68);
#pragma unroll
    for (int k4 = 0; k4 < 16; k4++) {
      float4 hv = hp[k4];
      h1v[4 * k4 + 0] = hv.x; h1v[4 * k4 + 1] = hv.y;
      h1v[4 * k4 + 2] = hv.z; h1v[4 * k4 + 3] = hv.w;
    }
    for (int j = 0; j < 13; j++) {
      int o = g * 13 + j;
      if (o < 198) {
        float iv = inv2L[o];
        float q0 = 0.f, q1 = 0.f, q2 = 0.f, q3 = 0.f;
        if (isb) {
          const ushort4* wr = (const ushort4*)w2r;
#pragma unroll
          for (int k4 = 0; k4 < 16; k4 += 4) {
            ushort4 u0 = wr[o * 16 + k4 + 0];
            ushort4 u1 = wr[o * 16 + k4 + 1];
            ushort4 u2 = wr[o * 16 + k4 + 2];
            ushort4 u3 = wr[o * 16 + k4 + 3];
            q0 = fmaf(bf2f(u0.x) * iv, h1v[4 * k4 + 0], q0);
            q0 = fmaf(bf2f(u0.y) * iv, h1v[4 * k4 + 1], q0);
            q0 = fmaf(bf2f(u0.z) * iv, h1v[4 * k4 + 2], q0);
            q0 = fmaf(bf2f(u0.w) * iv, h1v[4 * k4 + 3], q0);
            q1 = fmaf(bf2f(u1.x) * iv, h1v[4 * k4 + 4], q1);
            q1 = fmaf(bf2f(u1.y) * iv, h1v[4 * k4 + 5], q1);
            q1 = fmaf(bf2f(u1.z) * iv, h1v[4 * k4 + 6], q1);
            q1 = fmaf(bf2f(u1.w) * iv, h1v[4 * k4 + 7], q1);
            q2 = fmaf(bf2f(u2.x) * iv, h1v[4 * k4 + 8], q2);
            q2 = fmaf(bf2f(u2.y) * iv, h1v[4 * k4 + 9], q2);
            q2 = fmaf(bf2f(u2.z) * iv, h1v[4 * k4 + 10], q2);
            q2 = fmaf(bf2f(u2.w) * iv, h1v[4 * k4 + 11], q2);
            q3 = fmaf(bf2f(u3.x) * iv, h1v[4 * k4 + 12], q3);
            q3 = fmaf(bf2f(u3.y) * iv, h1v[4 * k4 + 13], q3);
            q3 = fmaf(bf2f(u3.z) * iv, h1v[4 * k4 + 14], q3);
            q3 = fmaf(bf2f(u3.w) * iv, h1v[4 * k4 + 15], q3);
          }
        } else {
          const float4* wr = (const float4*)w2r;
#pragma unroll
          for (int k4 = 0; k4 < 16; k4 += 4) {
            float4 w0 = wr[o * 16 + k4 + 0];
            float4 w1v = wr[o * 16 + k4 + 1];
            float4 w2v = wr[o * 16 + k4 + 2];
            float4 w3v = wr[o * 16 + k4 + 3];
            q0 = fmaf(w0.x * iv, h1v[4 * k4 + 0], q0);
            q0 = fmaf(w0.y * iv, h1v[4 * k4 + 1], q0);
            q0 = fmaf(w0.z * iv, h1v[4 * k4 + 2], q0);
            q0 = fmaf(w0.w * iv, h1v[4 * k4 + 3], q0);
            q1 = fmaf(w1v.x * iv, h1v[4 * k4 + 4], q1);
            q1 = fmaf(w1v.y * iv, h1v[4 * k4 + 5], q1);
            q1 = fmaf(w1v.z * iv, h1v[4 * k4 + 6], q1);
            q1 = fmaf(w1v.w * iv, h1v[4 * k4 + 7], q1);
            q2 = fmaf(w2v.x * iv, h1v[4 * k4 + 8], q2);
            q2 = fmaf(w2v.y * iv, h1v[4 * k4 + 9], q2);
            q2 = fmaf(w2v.z * iv, h1v[4 * k4 + 10], q2);
            q2 = fmaf(w2v.w * iv, h1v[4 * k4 + 11], q2);
            q3 = fmaf(w3v.x * iv, h1v[4 * k4 + 12], q3);
            q3 = fmaf(w3v.y * iv, h1v[4 * k4 + 13], q3);
            q3 = fmaf(w3v.z * iv, h1v[4 * k4 + 14], q3);
            q3 = fmaf(w3v.w * iv, h1v[4 * k4 + 15], q3);
          }
        }
        h2s[o * 16 + p] = b2fL[o] + ((q0 + q1) + (q2 + q3));
      }
    }
    __syncthreads();
    int r0 = g * 8, r1 = min(118, r0 + 8);
    float lm = -INFINITY;
    for (int o = r0; o < r1; o++) lm = fmaxf(lm, h2s[o * 16 + p]);
    smaxL[g * 16 + p] = lm;
    __syncthreads();
    float m = smaxL[p];
#pragma unroll
    for (int gg = 1; gg < 16; gg++) m = fmaxf(m, smaxL[gg * 16 + p]);
    float ls = 0.f;
    for (int o = r0; o < r1; o++) ls += expf(h2s[o * 16 + p] - m);
    ssumL[g * 16 + p] = ls;
    __syncthreads();
    float tot = 0.f;
#pragma unroll
    for (int gg = 0; gg < 16; gg++) tot += ssumL[gg * 16 + p];
    int h = t * 16 + p;
    for (int o = r0; o < r1; o++) {
      float dv = expf(h2s[o * 16 + p] - m) / tot;
      if (DLAY == 0) depthL[h * 120 + o] = dv;
      else           depthL[o * 33 + h] = dv;
    }
    int f0 = g * 5;
    for (int f = f0; f < f0 + 5; f++)
      featL[h * 80 + f] = h2s[(118 + f) * 16 + p];
    __syncthreads();   // shbuf reused next tile; depthL/featL complete after t=1
  }
}

__device__ __forceinline__ void dev_out_copy(
    int gtid, int gstride, const float* __restrict__ bevAcc,
    void* __restrict__ out, bool isb) {
  const float4* a4 = (const float4*)bevAcc;
  int n4 = (NBIN * 2 * C_OUT) / 4;
  if (isb) {
    ushort4* o4 = (ushort4*)out;
    for (int i = gtid; i < n4; i += gstride) {
      float4 v = a4[i];
      ushort4 o; o.x = f2bf(v.x); o.y = f2bf(v.y); o.z = f2bf(v.z); o.w = f2bf(v.w);
      o4[i] = o;
    }
  } else {
    float4* o4 = (float4*)out;
    for (int i = gtid; i < n4; i += gstride) o4[i] = a4[i];
  }
}

// ==================== K1: fused column MLP+PCOL (176) || bins (82) ====================
__global__ __launch_bounds__(256) void k_f1(
    const void* __restrict__ xraw,
    const void* __restrict__ rots, const void* __restrict__ trans,
    const void* __restrict__ intr,
    const void* __restrict__ w1r, const void* __restrict__ b1r,
    const void* __restrict__ g1r, const void* __restrict__ be1r,
    const void* __restrict__ m1r, const void* __restrict__ v1r,
    const void* __restrict__ w2r, const void* __restrict__ b2r,
    const void* __restrict__ g2r, const void* __restrict__ be2r,
    const void* __restrict__ m2r, const void* __restrict__ v2r,
    int* __restrict__ cnt, unsigned* __restrict__ ent, int* __restrict__ flag,
    float* __restrict__ P) {
  __shared__ __align__(16) float shbuf[3712];
  __shared__ __align__(16) float h1L[16 * 68];
  __shared__ float inv1L[64], b1fL[64], inv2L[198], b2fL[198];
  __shared__ __align__(16) float depthL[32 * 120];
  __shared__ __align__(16) float featL[32 * 80];
  __shared__ float radEL[129], angEL[257], camsL[46];
  int tid = threadIdx.x;
  bool isb = detect_bf16(intr);

  if (blockIdx.x >= 176) {
    dev_bins(blockIdx.x - 176, tid, radEL, angEL, camsL,
             rots, trans, intr, isb, cnt, ent, flag);
    return;
  }
  // XCD-chunked swizzle (round-7 proven): bijective, 176 = 8*22
  int col = (blockIdx.x & 7) * 22 + (blockIdx.x >> 3);
  int b = col / FW, w = col - b * FW;

  dev_mlp_col<0>(b, w, tid, shbuf, h1L, inv1L, b1fL, inv2L, b2fL,
                 depthL, featL, xraw, w1r, b1r, g1r, be1r, m1r, v1r,
                 w2r, b2r, g2r, be2r, m2r, v2r, isb);

  // pcol compute tail (verbatim proven)
  const float4* featL4 = (const float4*)featL;
  const float4* depthL4 = (const float4*)depthL;   // [h][30] quads
  float4* P4 = (float4*)(P + (size_t)col * PSTRIDE);
  for (int t2 = tid; t2 < 30 * 20; t2 += 256) {
    int dq = t2 / 20, c4 = t2 - dq * 20;
    float4 a0 = make_float4(0.f, 0.f, 0.f, 0.f);
    float4 a1 = make_float4(0.f, 0.f, 0.f, 0.f);
    float4 a2 = make_float4(0.f, 0.f, 0.f, 0.f);
    float4 a3 = make_float4(0.f, 0.f, 0.f, 0.f);
#pragma unroll
    for (int h = 0; h < FH; h++) {
      float4 wd = depthL4[h * 30 + dq];
      float4 f = featL4[h * 20 + c4];
      a0.x = fmaf(wd.x, f.x, a0.x); a0.y = fmaf(wd.x, f.y, a0.y);
      a0.z = fmaf(wd.x, f.z, a0.z); a0.w = fmaf(wd.x, f.w, a0.w);
      a1.x = fmaf(wd.y, f.x, a1.x); a1.y = fmaf(wd.y, f.y, a1.y);
      a1.z = fmaf(wd.y, f.z, a1.z); a1.w = fmaf(wd.y, f.w, a1.w);
      a2.x = fmaf(wd.z, f.x, a2.x); a2.y = fmaf(wd.z, f.y, a2.y);
      a2.z = fmaf(wd.z, f.z, a2.z); a2.w = fmaf(wd.z, f.w, a2.w);
      a3.x = fmaf(wd.w, f.x, a3.x); a3.y = fmaf(wd.w, f.y, a3.y);
      a3.z = fmaf(wd.w, f.z, a3.z); a3.w = fmaf(wd.w, f.w, a3.w);
    }
    int d0 = dq * 4;
    P4[(d0 + 0) * 20 + c4] = a0;
    P4[(d0 + 1) * 20 + c4] = a1;
    if (d0 + 2 < DD) {
      P4[(d0 + 2) * 20 + c4] = a2;
      P4[(d0 + 3) * 20 + c4] = a3;
    }
  }
}

// ==================== K2: outg de-scratched (256) || flag-guarded bevAcc zero (64) ====================
// Entry arrays fully register-resident: Batcher odd-even merge network on 16
// padded keys (all static indices; unique keys -> same sorted order as the
// proven insertion sort) + entry-outer/20-wide-row-inner accumulation (20
// independent 16B loads per entry, i-ascending adds per (bin,c4) -> bit-exact).
__global__ __launch_bounds__(256) void k_f2(
    const float* __restrict__ P, const int* __restrict__ cnt,
    const unsigned* __restrict__ ent, const int* __restrict__ flag,
    float* __restrict__ bevAcc, void* __restrict__ out,
    const void* __restrict__ intrRaw) {
  int tid = threadIdx.x;
  if (blockIdx.x >= 256) {
    if (*flag == 0) return;               // happy path: no 21 MB zero
    float4 z = make_float4(0.f, 0.f, 0.f, 0.f);
    float4* bz = (float4*)bevAcc;
    int n4 = (NBIN * 2 * C_OUT) / 4;
    for (int i = (blockIdx.x - 256) * 256 + tid; i < n4; i += 64 * 256) bz[i] = z;
    return;
  }
  if (*flag != 0) return;
  bool isb = detect_bf16(intrRaw);
  int b = blockIdx.x >> 7;                // 128 tasks per batch
  int ri = blockIdx.x & 127;
  int bin = ri * N_THETA + tid;
  int n = cnt[b * NBIN + bin];
  if (n > ECAP) n = ECAP;
  const unsigned* eb = ent + (size_t)(b * NBIN + bin) * ECAP;
  unsigned ee[16];
#pragma unroll
  for (int i = 0; i < ECAP; i++) ee[i] = (i < n) ? eb[i] : 0xFFFFFFFFu;
#pragma unroll
  for (int i = ECAP; i < 16; i++) ee[i] = 0xFFFFFFFFu;
  // Batcher odd-even mergesort, 16 inputs (classic iterative form; compile-time
  // loop bounds -> fully unrolled -> all ee[] indices static -> registers).
#pragma unroll
  for (int p = 1; p < 16; p <<= 1) {
#pragma unroll
    for (int k = p; k >= 1; k >>= 1) {
#pragma unroll
      for (int j = k & (p - 1); j + k < 16; j += 2 * k) {
#pragma unroll
        for (int i = 0; i < k; i++) {
          if (i + j + k < 16) {
            if (((i + j) / (2 * p)) == ((i + j + k) / (2 * p))) {
              unsigned x = ee[i + j], y = ee[i + j + k];
              ee[i + j] = x < y ? x : y;
              ee[i + j + k] = x < y ? y : x;
            }
          }
        }
      }
    }
  }
  // accumulate: entry-outer, full 320B row per entry (20 parallel loads)
  float4 s[20];
#pragma unroll
  for (int c = 0; c < 20; c++) s[c] = make_float4(0.f, 0.f, 0.f, 0.f);
  const float4* P4 = (const float4*)P;
#pragma unroll
  for (int i = 0; i < ECAP; i++) {
    if (i < n) {
      const float4* row = P4 + (((ee[i] >> 8) * PSTRIDE + (ee[i] & 255u) * C_OUT) >> 2);
#pragma unroll
      for (int c = 0; c < 20; c++) {
        float4 v = row[c];
        s[c].x += v.x; s[c].y += v.y; s[c].z += v.z; s[c].w += v.w;
      }
    }
  }
  unsigned short* oh = (unsigned short*)out;
  float* of = (float*)out;
  size_t obase = (((size_t)(b * C_OUT)) << 15) + bin;
#pragma unroll
  for (int c4 = 0; c4 < 20; c4++) {
    size_t o0 = obase + ((size_t)(c4 * 4) << 15);
    if (isb) {
      oh[o0]              = f2bf(s[c4].x);
      oh[o0 + (1u << 15)] = f2bf(s[c4].y);
      oh[o0 + (2u << 15)] = f2bf(s[c4].z);
      oh[o0 + (3u << 15)] = f2bf(s[c4].w);
    } else {
      of[o0]              = s[c4].x;
      of[o0 + (1u << 15)] = s[c4].y;
      of[o0 + (2u << 15)] = s[c4].z;
      of[o0 + (3u << 15)] = s[c4].w;
    }
  }
}

// ==================== K3: flag-guarded fallback = recompute MLP + scatter (176) ====================
__global__ __launch_bounds__(256) void k_f3(
    const void* __restrict__ xraw,
    const void* __restrict__ rots, const void* __restrict__ trans,
    const void* __restrict__ intr,
    const void* __restrict__ w1r, const void* __restrict__ b1r,
    const void* __restrict__ g1r, const void* __restrict__ be1r,
    const void* __restrict__ m1r, const void* __restrict__ v1r,
    const void* __restrict__ w2r, const void* __restrict__ b2r,
    const void* __restrict__ g2r, const void* __restrict__ be2r,
    const void* __restrict__ m2r, const void* __restrict__ v2r,
    const int* __restrict__ flag, float* __restrict__ bevAcc) {
  __shared__ __align__(16) float shbuf[3712];
  __shared__ __align__(16) float h1L[16 * 68];
  __shared__ float inv1L[64], b1fL[64], inv2L[198], b2fL[198];
  __shared__ __align__(16) float depthL[DD * 33];
  __shared__ __align__(16) float featL[32 * 80];
  __shared__ float radEL[129], angEL[257], camsL[46];
  if (*flag == 0) return;
  int tid = threadIdx.x;
  bool isb = detect_bf16(intr);
  int col = blockIdx.x;
  int b = col / FW, w = col - b * FW;
  load_geom(tid, radEL, angEL, camsL, rots, trans, intr, isb);
  dev_mlp_col<1>(b, w, tid, shbuf, h1L, inv1L, b1fL, inv2L, b2fL,
                 depthL, featL, xraw, w1r, b1r, g1r, be1r, m1r, v1r,
                 w2r, b2r, g2r, be2r, m2r, v2r, isb);
  const float4* featL4 = (const float4*)featL;
  for (int t = tid; t < DD * FH * 20; t += 256) {
    int d = t / 640, rem = t - d * 640;
    int h = rem / 20, c4 = rem - h * 20;
    int bin = computeBin(w, h, d, camsL, b, radEL, angEL);
    if (bin < 0) continue;
    float wd = depthL[d * 33 + h];
    float4 f = featL4[h * 20 + c4];
    float* outb = bevAcc + (((size_t)(b * C_OUT + c4 * 4)) << 15) + bin;
    unsafeAtomicAdd(outb, wd * f.x);
    unsafeAtomicAdd(outb + (1u << 15), wd * f.y);
    unsafeAtomicAdd(outb + (2u << 15), wd * f.z);
    unsafeAtomicAdd(outb + (3u << 15), wd * f.w);
  }
}

// ==================== K4: flag-guarded copy (320) ====================
__global__ __launch_bounds__(256) void k_f4(
    const float* __restrict__ bevAcc, const int* __restrict__ flag,
    void* __restrict__ out, const void* __restrict__ intrRaw) {
  if (*flag == 0) return;
  bool isb = detect_bf16(intrRaw);
  dev_out_copy(blockIdx.x * 256 + threadIdx.x, 320 * 256, bevAcc, out, isb);
}

extern "C" void kernel_launch(void* const* d_in, const int* in_sizes, int n_in,
                              void* d_out, int out_size, void* d_ws, size_t ws_size,
                              hipStream_t stream) {
  const void* x     = d_in[0];
  const void* rots  = d_in[1];
  const void* trans = d_in[2];
  const void* intr  = d_in[3];
  const void* w1  = d_in[4];
  const void* b1  = d_in[5];
  const void* g1  = d_in[6];
  const void* be1 = d_in[7];
  const void* m1  = d_in[8];
  const void* v1  = d_in[9];
  const void* w2  = d_in[10];
  const void* b2  = d_in[11];
  const void* g2  = d_in[12];
  const void* be2 = d_in[13];
  const void* m2  = d_in[14];
  const void* v2  = d_in[15];

  float* ws = (float*)d_ws;                     // offsets in floats
  float*    P      = ws + 0;                    // 1,661,440 f
  int*      cnt    = (int*)(ws + 1661440);      // 65,536 i
  int*      flag   = (int*)(ws + 1726976);      // 1 i (reserve 64; contiguous after cnt)
  unsigned* ent    = (unsigned*)(ws + 1727040); // 786,432 u32 -> ends 2,513,472
  float*    bevAcc = ws + 3628608;              // 5,242,880 f (fallback accumulator)

  (void)hipMemsetAsync(cnt, 0, (size_t)(65536 + 64) * sizeof(int), stream);

  k_f1<<<258, 256, 0, stream>>>(x, rots, trans, intr,
                                w1, b1, g1, be1, m1, v1,
                                w2, b2, g2, be2, m2, v2,
                                cnt, ent, flag, P);
  k_f2<<<320, 256, 0, stream>>>(P, cnt, ent, flag, bevAcc, d_out, intr);
  k_f3<<<176, 256, 0, stream>>>(x, rots, trans, intr,
                                w1, b1, g1, be1, m1, v1,
                                w2, b2, g2, be2, m2, v2, flag, bevAcc);
  k_f4<<<320, 256, 0, stream>>>(bevAcc, flag, d_out, intr);
}